// Round 2
// baseline (1982.199 us; speedup 1.0000x reference)
//
#include <hip/hip_runtime.h>

#define TT 1000
#define FF 20
#define HH 256
#define OO 200
#define ZR 256           // zero-row index in padded int32 tables (257 rows x 256 cols)

typedef unsigned int uint;

struct __align__(16) ll2 { long long x, y; };

__device__ __forceinline__ int rfl(int v) { return __builtin_amdgcn_readfirstlane(v); }

// Dual-table signed toggle-gather batch: N rows from toggle mask m (wave-uniform),
// sign from current mask cur. Both tables share row indices -> one scalar stream,
// 2N 16B loads in flight. Empty slots hit zero row ZR. Exact int64 accumulation:
// (v ^ sm) - sm negates when sm = -1.
template<int N>
__device__ __forceinline__ void gstep2(const int* __restrict__ tabA, const int* __restrict__ tabB,
                                       uint& m, uint cur, int rowbase, int cx,
                                       long long* accA, long long* accB) {
    const int* pA[N];
    const int* pB[N];
    int sm[N];
#pragma unroll
    for (int u = 0; u < N; ++u) {
        int bb = __ffs((int)m);
        int k  = (bb ? bb : 1) - 1;
        int row = rfl(bb ? (rowbase + k) : ZR);
        int pos = rfl(bb ? (int)((cur >> k) & 1u) : 1);
        sm[u] = pos ? 0 : -1;
        size_t off = ((size_t)row << 8) + (size_t)cx;
        pA[u] = tabA + off;
        pB[u] = tabB + off;
        m &= (m - 1u);
    }
    int4 va[N], vb[N];
#pragma unroll
    for (int u = 0; u < N; ++u) { va[u] = *(const int4*)pA[u]; vb[u] = *(const int4*)pB[u]; }
#pragma unroll
    for (int u = 0; u < N; ++u) {
        accA[0] += (long long)((va[u].x ^ sm[u]) - sm[u]);
        accA[1] += (long long)((va[u].y ^ sm[u]) - sm[u]);
        accA[2] += (long long)((va[u].z ^ sm[u]) - sm[u]);
        accA[3] += (long long)((va[u].w ^ sm[u]) - sm[u]);
        accB[0] += (long long)((vb[u].x ^ sm[u]) - sm[u]);
        accB[1] += (long long)((vb[u].y ^ sm[u]) - sm[u]);
        accB[2] += (long long)((vb[u].z ^ sm[u]) - sm[u]);
        accB[3] += (long long)((vb[u].w ^ sm[u]) - sm[u]);
    }
}

// Adaptive-depth dual signed toggle gather into PERSISTENT per-wave register
// partials, then plain b128 writes of the partial into this wave's private LDS
// slice. No atomics, no cross-wave contention; int64 => exact & order-free.
__device__ __forceinline__ void gather2(const int* __restrict__ tabA, const int* __restrict__ tabB,
                                        uint m, uint cur, int rowbase, int cx,
                                        long long* accA, long long* accB,
                                        long long* dstA, long long* dstB) {
    while (m) {
        int pc = rfl(__popc(m));
        if (pc > 4)      gstep2<8>(tabA, tabB, m, cur, rowbase, cx, accA, accB);
        else if (pc > 2) gstep2<4>(tabA, tabB, m, cur, rowbase, cx, accA, accB);
        else             gstep2<2>(tabA, tabB, m, cur, rowbase, cx, accA, accB);
    }
    ll2 v;
    v.x = accA[0]; v.y = accA[1]; *(ll2*)(dstA + cx)     = v;
    v.x = accA[2]; v.y = accA[3]; *(ll2*)(dstA + cx + 2) = v;
    v.x = accB[0]; v.y = accB[1]; *(ll2*)(dstB + cx)     = v;
    v.x = accB[2]; v.y = accB[3]; *(ll2*)(dstB + cx + 2) = v;
}

// Sum the 8 per-wave partial slices for one drive at column j (exact int64).
__device__ __forceinline__ long long sum8(const long long* __restrict__ base, int j) {
    long long t0 = base[0 * HH + j], t1 = base[1 * HH + j];
    long long t2 = base[2 * HH + j], t3 = base[3 * HH + j];
    long long t4 = base[4 * HH + j], t5 = base[5 * HH + j];
    long long t6 = base[6 * HH + j], t7 = base[7 * HH + j];
    return ((t0 + t1) + (t2 + t3)) + ((t4 + t5) + (t6 + t7));
}

#define INV30 9.31322574615478515625e-10   // 2^-30, exact

// 2-barrier software pipeline. Iteration i:
//   Phase A: B(i) [waves 0-3] || D(i-1) [waves 4-7] || wx(i+1) [waves 8-11]
//            || x prefetch (i+2) || F(i-2) [wave 15]
//   Phase B: dual-gather t1(i): (W2Tq,V1q)->(part W2,V1) [waves 0-7]
//            dual-gather t2(i-1): (WTq,V2q)->(part O,V2) [waves 8-15]
// Drives stored as part[drive][wave][256] int64 partials; update threads sum 8.
__global__ __launch_bounds__(1024, 1) void snn_main(
    const float* __restrict__ x,
    const float* __restrict__ W1, const float* __restrict__ b1,
    const float* __restrict__ beta1,
    const float* __restrict__ b2, const float* __restrict__ beta2,
    const int* __restrict__ V1q, const int* __restrict__ V2q,
    const int* __restrict__ W2Tq, const int* __restrict__ WTq,
    const float* __restrict__ alpha_out, const float* __restrict__ beta_out,
    float* __restrict__ out)
{
    __shared__ float w1t_s[FF * HH];     // W1 transposed [f][h] (fp32, exact drive)
    __shared__ float wx_s[2][HH];        // b1 + W1 x_t, double-buffered by t parity
    __shared__ float xts[2][FF];         // x[t] double buffer
    // per-wave drive partials: [drive][wave][col], drive: 0=V1 1=W2 2=V2 3=O
    __shared__ __align__(16) long long part_s[4 * 8 * HH];   // 64 KB
    __shared__ uint m1s[8], m2s[8];      // current 256-bit spike masks (8x32)
    __shared__ uint t1s[8], t2s[8];      // toggle masks this step

    const int tid = threadIdx.x;
    const int b   = blockIdx.x;
    const float* xg = x + (size_t)b * TT * FF;

#define PSL(d, w) (part_s + (((d) * 8 + (w)) << 8))

    // ---- init ----
    for (int idx = tid; idx < FF * HH; idx += 1024) {
        int h = idx / FF, f = idx - h * FF;
        w1t_s[f * HH + h] = W1[idx];
    }
    for (int idx = tid; idx < 4 * 8 * HH; idx += 1024) part_s[idx] = 0;
    if (tid < FF) { xts[0][tid] = xg[tid]; xts[1][tid] = xg[FF + tid]; }
    if (tid < 8) { m1s[tid] = 0u; m2s[tid] = 0u; t1s[tid] = 0u; t2s[tid] = 0u; }

    // persistent gather partial registers (role-dependent use)
    long long pacA[4] = {0, 0, 0, 0};
    long long pacB[4] = {0, 0, 0, 0};

    // layer-1 state on tid 0..255
    float syn1 = 0.f, mem1 = 0.f, beta1r = 0.f;
    bool spk1 = false;
    if (tid < HH) beta1r = beta1[tid];

    // layer-2 state on tid 256..511
    float syn2 = 0.f, mem2 = 0.f, beta2r = 0.f, b2r = 0.f;
    bool spk2 = false;
    if (tid >= HH && tid < 2 * HH) { beta2r = beta2[tid - HH]; b2r = b2[tid - HH]; }

    // wx-compute bias on tid 512..767
    float b1r2 = 0.f;
    if (tid >= 512 && tid < 768) b1r2 = b1[tid - 512];

    // output state on tid 960..1023
    float synO[4] = {0,0,0,0}, memO[4] = {0,0,0,0}, accO[4] = {0,0,0,0};
    float aOr[4] = {0,0,0,0}, bOr[4] = {0,0,0,0};
    bool  spkO[4] = {false,false,false,false};
    if (tid >= 960) {
        int o0 = tid - 960;
#pragma unroll
        for (int r = 0; r < 4; ++r) {
            int o = o0 + (r << 6);
            if (o < OO) { aOr[r] = alpha_out[o]; bOr[r] = beta_out[o]; }
        }
    }
    __syncthreads();
    if (tid < HH) {   // wx for t=0
        float wx = b1[tid];
#pragma unroll
        for (int f = 0; f < FF; ++f) wx = fmaf(xts[0][f], w1t_s[f * HH + tid], wx);
        wx_s[0][tid] = wx;
    }
    __syncthreads();

    for (int i = 0; i < TT + 2; ++i) {
        // ================= Phase A =================
        if (tid < HH) {
            // B(i): layer-1 update, emit m1 + toggle t1
            if (i < TT) {
                long long s1 = sum8(PSL(0, 0), tid);
                float g1 = (float)((double)s1 * INV30);
                syn1 = fmaf(0.95f, syn1, wx_s[i & 1][tid] + g1);
                mem1 = fmaf(beta1r, mem1, syn1) - (spk1 ? 1.f : 0.f);
                spk1 = mem1 > 1.0f;
                unsigned long long bal = __ballot(spk1 ? 1 : 0);
                if ((tid & 63) == 0) {
                    int w = tid >> 6;
                    uint n0 = (uint)bal, n1 = (uint)(bal >> 32);
                    t1s[2*w]   = m1s[2*w]   ^ n0;
                    t1s[2*w+1] = m1s[2*w+1] ^ n1;
                    m1s[2*w]   = n0;
                    m1s[2*w+1] = n1;
                }
            }
        } else if (tid < 2 * HH) {
            // D(i-1): layer-2 update, emit m2 + toggle t2
            if (i >= 1 && i <= TT) {
                int j = tid - HH;
                long long sA = sum8(PSL(1, 0), j);
                long long sB = sum8(PSL(2, 0), j);
                float gA = (float)((double)sA * INV30);
                float gB = (float)((double)sB * INV30);
                syn2 = fmaf(0.95f, syn2, b2r + gA + gB);
                mem2 = fmaf(beta2r, mem2, syn2) - (spk2 ? 1.f : 0.f);
                spk2 = mem2 > 1.0f;
                unsigned long long bal = __ballot(spk2 ? 1 : 0);
                if ((tid & 63) == 0) {
                    int w = j >> 6;
                    uint n0 = (uint)bal, n1 = (uint)(bal >> 32);
                    t2s[2*w]   = m2s[2*w]   ^ n0;
                    t2s[2*w+1] = m2s[2*w+1] ^ n1;
                    m2s[2*w]   = n0;
                    m2s[2*w+1] = n1;
                }
            }
        } else if (tid < 768) {
            // wx(i+1) into wx_s[(i+1)&1]
            if ((i + 1) < TT) {
                int j2 = tid - 512;
                const float* xx = xts[(i + 1) & 1];
                float wx = b1r2;
#pragma unroll
                for (int f = 0; f < FF; ++f) wx = fmaf(xx[f], w1t_s[f * HH + j2], wx);
                wx_s[(i + 1) & 1][j2] = wx;
            }
        } else if (tid < 768 + FF) {
            // prefetch x(i+2) into xts[i&1]
            if ((i + 2) < TT) xts[i & 1][tid - 768] = xg[(size_t)(i + 2) * FF + (tid - 768)];
        }
        // F(i-2): output layer (wave 15; disjoint from all branches above)
        if (tid >= 960 && i >= 2) {
            int tF = i - 2;
            int o0 = tid - 960;
            float mmax = -3.402823466e38f;
#pragma unroll
            for (int r = 0; r < 4; ++r) {
                int o = o0 + (r << 6);
                if (o < OO) {
                    long long so = sum8(PSL(3, 0), o);
                    float ot = (float)((double)so * INV30);
                    synO[r] = fmaf(aOr[r], synO[r], ot);
                    memO[r] = fmaf(bOr[r], memO[r], synO[r]) - (spkO[r] ? 1.f : 0.f);
                    spkO[r] = memO[r] > 1.0f;
                    mmax = fmaxf(mmax, memO[r]);
                }
            }
#pragma unroll
            for (int off = 32; off; off >>= 1) mmax = fmaxf(mmax, __shfl_xor(mmax, off, 64));
            float ex[4]; float se = 0.f;
#pragma unroll
            for (int r = 0; r < 4; ++r) {
                int o = o0 + (r << 6);
                ex[r] = (o < OO) ? expf(memO[r] - mmax) : 0.f;
                se += ex[r];
            }
#pragma unroll
            for (int off = 32; off; off >>= 1) se += __shfl_xor(se, off, 64);
            if (tF > 10) {
#pragma unroll
                for (int r = 0; r < 4; ++r) accO[r] += ex[r] / se;
            }
        }
        __syncthreads();
        // ================= Phase B =================
        if (tid < 512) {
            // C(i): dual gather on t1(i) -> part W2 (A), part V1 (B)
            if (i < TT) {
                int e = tid >> 6, cq = tid & 63;
                uint tm = (uint)rfl((int)t1s[e]);
                if (tm) {
                    uint cm = (uint)rfl((int)m1s[e]);
                    gather2(W2Tq, V1q, tm, cm, e << 5, cq << 2,
                            pacA, pacB, PSL(1, e), PSL(0, e));
                }
            }
        } else {
            // E(i-1): dual gather on t2(i-1) -> part O (A), part V2 (B)
            if (i >= 1 && i <= TT) {
                int tt2 = tid - 512;
                int e = tt2 >> 6, cq = tt2 & 63;
                uint tm = (uint)rfl((int)t2s[e]);
                if (tm) {
                    uint cm = (uint)rfl((int)m2s[e]);
                    gather2(WTq, V2q, tm, cm, e << 5, cq << 2,
                            pacA, pacB, PSL(3, e), PSL(2, e));
                }
            }
        }
        __syncthreads();
    }

    if (tid >= 960) {
        int o0 = tid - 960;
#pragma unroll
        for (int r = 0; r < 4; ++r) {
            int o = o0 + (r << 6);
            if (o < OO) out[(size_t)b * OO + o] = accO[r];
        }
    }
}

// one-shot prep: padded 257x256 int32 fixed-point (2^30) tables, zero diagonal
// (V1q/V2q), zero row 256, WTq cols >= 200 zero.
__global__ void prep_kernel(const float* __restrict__ Vrec1, const float* __restrict__ Vrec2,
                            const float* __restrict__ W2, const float* __restrict__ Wout,
                            int* __restrict__ V1q, int* __restrict__ V2q,
                            int* __restrict__ W2Tq, int* __restrict__ WTq) {
    int idx = blockIdx.x * blockDim.x + threadIdx.x;   // 257*256 entries
    if (idx >= 257 * 256) return;
    int r = idx >> 8, c = idx & 255;
    float v1 = 0.f, v2 = 0.f, w2 = 0.f, wo = 0.f;
    if (r < 256) {
        if (r != c) { v1 = Vrec1[r * HH + c]; v2 = Vrec2[r * HH + c]; }
        w2 = W2[c * HH + r];
        if (c < OO) wo = Wout[c * HH + r];
    }
    const float S = 1073741824.0f;   // 2^30
    V1q[idx]  = __float2int_rn(v1 * S);
    V2q[idx]  = __float2int_rn(v2 * S);
    W2Tq[idx] = __float2int_rn(w2 * S);
    WTq[idx]  = __float2int_rn(wo * S);
}

extern "C" void kernel_launch(void* const* d_in, const int* in_sizes, int n_in,
                              void* d_out, int out_size, void* d_ws, size_t ws_size,
                              hipStream_t stream) {
    const float* x       = (const float*)d_in[0];
    const float* W1      = (const float*)d_in[1];
    const float* b1      = (const float*)d_in[2];
    const float* Vrec1   = (const float*)d_in[3];
    const float* beta1   = (const float*)d_in[4];
    const float* W2      = (const float*)d_in[5];
    const float* b2      = (const float*)d_in[6];
    const float* Vrec2   = (const float*)d_in[7];
    const float* beta2   = (const float*)d_in[8];
    const float* Wout    = (const float*)d_in[9];
    const float* alpha_o = (const float*)d_in[10];
    const float* beta_o  = (const float*)d_in[11];

    const int TBL = 257 * 256;       // int32 per padded table
    int* V1q  = (int*)d_ws;
    int* V2q  = V1q + TBL;
    int* W2Tq = V2q + TBL;
    int* WTq  = W2Tq + TBL;          // total ~1.05 MB of ws

    prep_kernel<<<(TBL + 255) / 256, 256, 0, stream>>>(Vrec1, Vrec2, W2, Wout,
                                                       V1q, V2q, W2Tq, WTq);
    snn_main<<<128, 1024, 0, stream>>>(x, W1, b1, beta1, b2, beta2,
                                       V1q, V2q, W2Tq, WTq,
                                       alpha_o, beta_o, (float*)d_out);
}

// Round 3
// 1929.661 us; speedup vs baseline: 1.0272x; 1.0272x over previous
//
#include <hip/hip_runtime.h>

#define TT 1000
#define FF 20
#define HH 256
#define OO 200
#define ZR 256           // zero-row index in padded int32 tables (257 rows x 256 cols)

typedef unsigned int uint;
typedef unsigned long long ull;

__device__ __forceinline__ int rfl(int v) { return __builtin_amdgcn_readfirstlane(v); }

// Dual-table signed toggle-gather batch: N rows from toggle mask m (wave-uniform),
// sign from current mask cur. Both tables share row indices -> one scalar stream,
// 2N 16B loads in flight. Empty slots hit zero row ZR. Exact int64 accumulation:
// (v ^ sm) - sm negates when sm = -1.
template<int N>
__device__ __forceinline__ void gstep2(const int* __restrict__ tabA, const int* __restrict__ tabB,
                                       uint& m, uint cur, int rowbase, int cx,
                                       long long* accA, long long* accB) {
    const int* pA[N];
    const int* pB[N];
    int sm[N];
#pragma unroll
    for (int u = 0; u < N; ++u) {
        int bb = __ffs((int)m);
        int k  = (bb ? bb : 1) - 1;
        int row = rfl(bb ? (rowbase + k) : ZR);
        int pos = rfl(bb ? (int)((cur >> k) & 1u) : 1);
        sm[u] = pos ? 0 : -1;
        size_t off = ((size_t)row << 8) + (size_t)cx;
        pA[u] = tabA + off;
        pB[u] = tabB + off;
        m &= (m - 1u);
    }
    int4 va[N], vb[N];
#pragma unroll
    for (int u = 0; u < N; ++u) { va[u] = *(const int4*)pA[u]; vb[u] = *(const int4*)pB[u]; }
#pragma unroll
    for (int u = 0; u < N; ++u) {
        accA[0] += (long long)((va[u].x ^ sm[u]) - sm[u]);
        accA[1] += (long long)((va[u].y ^ sm[u]) - sm[u]);
        accA[2] += (long long)((va[u].z ^ sm[u]) - sm[u]);
        accA[3] += (long long)((va[u].w ^ sm[u]) - sm[u]);
        accB[0] += (long long)((vb[u].x ^ sm[u]) - sm[u]);
        accB[1] += (long long)((vb[u].y ^ sm[u]) - sm[u]);
        accB[2] += (long long)((vb[u].z ^ sm[u]) - sm[u]);
        accB[3] += (long long)((vb[u].w ^ sm[u]) - sm[u]);
    }
}

// Adaptive-depth dual signed toggle gather; zero-row waste <= 3 per batch.
// Committed via LDS int64 atomics (exact, order-free). Called only when m != 0.
__device__ __forceinline__ void gather2(const int* __restrict__ tabA, const int* __restrict__ tabB,
                                        uint m, uint cur, int rowbase, int cx,
                                        long long* dstA, long long* dstB) {
    long long accA[4] = {0, 0, 0, 0}, accB[4] = {0, 0, 0, 0};
    while (m) {
        int pc = rfl(__popc(m));
        if (pc > 4)      gstep2<8>(tabA, tabB, m, cur, rowbase, cx, accA, accB);
        else if (pc > 2) gstep2<4>(tabA, tabB, m, cur, rowbase, cx, accA, accB);
        else             gstep2<2>(tabA, tabB, m, cur, rowbase, cx, accA, accB);
    }
#pragma unroll
    for (int c = 0; c < 4; ++c) {
        atomicAdd((ull*)&dstA[cx + c], (ull)accA[c]);
        atomicAdd((ull*)&dstB[cx + c], (ull)accB[c]);
    }
}

#define INV30 9.31322574615478515625e-10   // 2^-30, exact

// 8-wave (512-thread) 2-barrier pipeline; masks and wx live in registers.
// Wave w (0-3): L1 neurons 64w..64w+63. Phase A: L1 update(i) + ballot (mask in
//   regs) + wx(i+1) for own neuron. Phase B: dual gather (W2Tq,V1q) on own
//   toggle words -> pW2q,pV1q. Wave 0 also prefetches x(i+2) (issue in A,
//   LDS-commit at end of B).
// Wave w (4-7): L2 neurons 64(w-4)... Phase A: L2 update(i-1) + ballot; wave 7
//   then runs output layer F(i-2). Phase B: dual gather (WTq,V2q) -> pOq,pV2q.
__global__ __launch_bounds__(512, 1) void snn_main(
    const float* __restrict__ x,
    const float* __restrict__ W1, const float* __restrict__ b1,
    const float* __restrict__ beta1,
    const float* __restrict__ b2, const float* __restrict__ beta2,
    const int* __restrict__ V1q, const int* __restrict__ V2q,
    const int* __restrict__ W2Tq, const int* __restrict__ WTq,
    const float* __restrict__ alpha_out, const float* __restrict__ beta_out,
    float* __restrict__ out)
{
    __shared__ float w1t_s[FF * HH];     // W1 transposed [f][h] (fp32, exact drive)
    __shared__ float xts[2][FF];         // x[t] double buffer
    __shared__ long long pV1q[HH];       // persistent int64 drives (scale 2^-30)
    __shared__ long long pV2q[HH];
    __shared__ long long pW2q[HH];
    __shared__ long long pOq[HH];

    const int tid  = threadIdx.x;
    const int wid  = tid >> 6;
    const int lane = tid & 63;
    const int b    = blockIdx.x;
    const float* xg = x + (size_t)b * TT * FF;

    // ---- init ----
    for (int idx = tid; idx < FF * HH; idx += 512) {
        int h = idx / FF, f = idx - h * FF;
        w1t_s[f * HH + h] = W1[idx];
    }
    if (tid < FF) { xts[0][tid] = xg[tid]; xts[1][tid] = xg[FF + tid]; }
    if (tid < HH) { pV1q[tid] = 0; pV2q[tid] = 0; pW2q[tid] = 0; pOq[tid] = 0; }

    // layer-1 state + wx register (tid 0..255)
    float syn1 = 0.f, mem1 = 0.f, beta1r = 0.f, b1r = 0.f, wxv = 0.f;
    bool spk1 = false;
    ull cur1 = 0ull, tog1 = 0ull;
    if (tid < HH) { beta1r = beta1[tid]; b1r = b1[tid]; }

    // layer-2 state (tid 256..511)
    float syn2 = 0.f, mem2 = 0.f, beta2r = 0.f, b2r = 0.f;
    bool spk2 = false;
    ull cur2 = 0ull, tog2 = 0ull;
    if (tid >= HH) { beta2r = beta2[tid - HH]; b2r = b2[tid - HH]; }

    // output state (wave 7: tid 448..511, lane o0 = tid-448, 4 outputs each)
    float synO[4] = {0,0,0,0}, memO[4] = {0,0,0,0}, accO[4] = {0,0,0,0};
    float aOr[4] = {0,0,0,0}, bOr[4] = {0,0,0,0};
    bool  spkO[4] = {false,false,false,false};
    if (wid == 7) {
#pragma unroll
        for (int r = 0; r < 4; ++r) {
            int o = lane + (r << 6);
            if (o < OO) { aOr[r] = alpha_out[o]; bOr[r] = beta_out[o]; }
        }
    }
    __syncthreads();
    if (tid < HH) {   // wx for t=0
        float wx = b1r;
#pragma unroll
        for (int f = 0; f < FF; ++f) wx = fmaf(xts[0][f], w1t_s[f * HH + tid], wx);
        wxv = wx;
    }
    __syncthreads();

    float xpf = 0.f;   // x-prefetch register (wave 0, lanes < FF)

    for (int i = 0; i < TT + 2; ++i) {
        // ================= Phase A =================
        if (wid == 0 && lane < FF && (i + 2) < TT)
            xpf = xg[(size_t)(i + 2) * FF + lane];   // issue early; commit end of B
        if (tid < HH) {
            // B(i): layer-1 update; ballot kept in registers; then wx(i+1)
            if (i < TT) {
                float g1 = (float)((double)pV1q[tid] * INV30);
                syn1 = fmaf(0.95f, syn1, wxv + g1);
                mem1 = fmaf(beta1r, mem1, syn1) - (spk1 ? 1.f : 0.f);
                spk1 = mem1 > 1.0f;
                ull bal = __ballot(spk1 ? 1 : 0);
                tog1 = cur1 ^ bal;
                cur1 = bal;
                if ((i + 1) < TT) {
                    const float* xx = xts[(i + 1) & 1];
                    float wx = b1r;
#pragma unroll
                    for (int f = 0; f < FF; ++f) wx = fmaf(xx[f], w1t_s[f * HH + tid], wx);
                    wxv = wx;
                }
            }
        } else {
            // D(i-1): layer-2 update; ballot kept in registers
            if (i >= 1 && i <= TT) {
                int j = tid - HH;
                float gA = (float)((double)pW2q[j] * INV30);
                float gB = (float)((double)pV2q[j] * INV30);
                syn2 = fmaf(0.95f, syn2, b2r + gA + gB);
                mem2 = fmaf(beta2r, mem2, syn2) - (spk2 ? 1.f : 0.f);
                spk2 = mem2 > 1.0f;
                ull bal = __ballot(spk2 ? 1 : 0);
                tog2 = cur2 ^ bal;
                cur2 = bal;
            }
            // F(i-2): output layer (wave 7, after its update; reads pOq before
            // E(i-1) rewrites it in phase B)
            if (wid == 7 && i >= 2) {
                int tF = i - 2;
                float mmax = -3.402823466e38f;
#pragma unroll
                for (int r = 0; r < 4; ++r) {
                    int o = lane + (r << 6);
                    if (o < OO) {
                        float ot = (float)((double)pOq[o] * INV30);
                        synO[r] = fmaf(aOr[r], synO[r], ot);
                        memO[r] = fmaf(bOr[r], memO[r], synO[r]) - (spkO[r] ? 1.f : 0.f);
                        spkO[r] = memO[r] > 1.0f;
                        mmax = fmaxf(mmax, memO[r]);
                    }
                }
#pragma unroll
                for (int off = 32; off; off >>= 1) mmax = fmaxf(mmax, __shfl_xor(mmax, off, 64));
                float ex[4]; float se = 0.f;
#pragma unroll
                for (int r = 0; r < 4; ++r) {
                    int o = lane + (r << 6);
                    ex[r] = (o < OO) ? expf(memO[r] - mmax) : 0.f;
                    se += ex[r];
                }
#pragma unroll
                for (int off = 32; off; off >>= 1) se += __shfl_xor(se, off, 64);
                if (tF > 10) {
#pragma unroll
                    for (int r = 0; r < 4; ++r) accO[r] += ex[r] / se;
                }
            }
        }
        __syncthreads();
        // ================= Phase B =================
        if (wid < 4) {
            // C(i): dual gather on own toggle words -> pW2q, pV1q
            if (i < TT && tog1) {
                uint tlo = (uint)rfl((int)(uint)tog1);
                uint thi = (uint)rfl((int)(uint)(tog1 >> 32));
                uint clo = (uint)rfl((int)(uint)cur1);
                uint chi = (uint)rfl((int)(uint)(cur1 >> 32));
                int cx = lane << 2;
                int rb = wid << 6;
                if (tlo) gather2(W2Tq, V1q, tlo, clo, rb,      cx, pW2q, pV1q);
                if (thi) gather2(W2Tq, V1q, thi, chi, rb + 32, cx, pW2q, pV1q);
            }
            if (wid == 0 && lane < FF && (i + 2) < TT) xts[i & 1][lane] = xpf;
        } else {
            // E(i-1): dual gather on own toggle words -> pOq, pV2q
            if (i >= 1 && i <= TT && tog2) {
                uint tlo = (uint)rfl((int)(uint)tog2);
                uint thi = (uint)rfl((int)(uint)(tog2 >> 32));
                uint clo = (uint)rfl((int)(uint)cur2);
                uint chi = (uint)rfl((int)(uint)(cur2 >> 32));
                int cx = lane << 2;
                int rb = (wid - 4) << 6;
                if (tlo) gather2(WTq, V2q, tlo, clo, rb,      cx, pOq, pV2q);
                if (thi) gather2(WTq, V2q, thi, chi, rb + 32, cx, pOq, pV2q);
            }
        }
        __syncthreads();
    }

    if (wid == 7) {
#pragma unroll
        for (int r = 0; r < 4; ++r) {
            int o = lane + (r << 6);
            if (o < OO) out[(size_t)b * OO + o] = accO[r];
        }
    }
}

// one-shot prep: padded 257x256 int32 fixed-point (2^30) tables, zero diagonal
// (V1q/V2q), zero row 256, WTq cols >= 200 zero.
__global__ void prep_kernel(const float* __restrict__ Vrec1, const float* __restrict__ Vrec2,
                            const float* __restrict__ W2, const float* __restrict__ Wout,
                            int* __restrict__ V1q, int* __restrict__ V2q,
                            int* __restrict__ W2Tq, int* __restrict__ WTq) {
    int idx = blockIdx.x * blockDim.x + threadIdx.x;   // 257*256 entries
    if (idx >= 257 * 256) return;
    int r = idx >> 8, c = idx & 255;
    float v1 = 0.f, v2 = 0.f, w2 = 0.f, wo = 0.f;
    if (r < 256) {
        if (r != c) { v1 = Vrec1[r * HH + c]; v2 = Vrec2[r * HH + c]; }
        w2 = W2[c * HH + r];
        if (c < OO) wo = Wout[c * HH + r];
    }
    const float S = 1073741824.0f;   // 2^30
    V1q[idx]  = __float2int_rn(v1 * S);
    V2q[idx]  = __float2int_rn(v2 * S);
    W2Tq[idx] = __float2int_rn(w2 * S);
    WTq[idx]  = __float2int_rn(wo * S);
}

extern "C" void kernel_launch(void* const* d_in, const int* in_sizes, int n_in,
                              void* d_out, int out_size, void* d_ws, size_t ws_size,
                              hipStream_t stream) {
    const float* x       = (const float*)d_in[0];
    const float* W1      = (const float*)d_in[1];
    const float* b1      = (const float*)d_in[2];
    const float* Vrec1   = (const float*)d_in[3];
    const float* beta1   = (const float*)d_in[4];
    const float* W2      = (const float*)d_in[5];
    const float* b2      = (const float*)d_in[6];
    const float* Vrec2   = (const float*)d_in[7];
    const float* beta2   = (const float*)d_in[8];
    const float* Wout    = (const float*)d_in[9];
    const float* alpha_o = (const float*)d_in[10];
    const float* beta_o  = (const float*)d_in[11];

    const int TBL = 257 * 256;       // int32 per padded table
    int* V1q  = (int*)d_ws;
    int* V2q  = V1q + TBL;
    int* W2Tq = V2q + TBL;
    int* WTq  = W2Tq + TBL;          // total ~1.05 MB of ws

    prep_kernel<<<(TBL + 255) / 256, 256, 0, stream>>>(Vrec1, Vrec2, W2, Wout,
                                                       V1q, V2q, W2Tq, WTq);
    snn_main<<<128, 512, 0, stream>>>(x, W1, b1, beta1, b2, beta2,
                                      V1q, V2q, W2Tq, WTq,
                                      alpha_o, beta_o, (float*)d_out);
}

// Round 4
// 1549.872 us; speedup vs baseline: 1.2789x; 1.2450x over previous
//
#include <hip/hip_runtime.h>

#define TT 1000
#define FF 20
#define HH 256
#define OO 200
#define ZR 256           // zero-row index in padded int32 tables (257 rows x 256 cols)
#define DSTR 68          // padded lane-stride (int64) for delta buffers: bank-conflict-free

typedef unsigned int uint;
typedef unsigned long long ull;

__device__ __forceinline__ int rfl(int v) { return __builtin_amdgcn_readfirstlane(v); }

// Dual-table signed toggle-gather batch: N rows from toggle mask m (wave-uniform),
// sign from current mask cur. Both tables share row indices -> one scalar stream,
// 2N 16B loads in flight. Empty slots hit zero row ZR. Exact int64 accumulation:
// (v ^ sm) - sm negates when sm = -1.
template<int N>
__device__ __forceinline__ void gstep2(const int* __restrict__ tabA, const int* __restrict__ tabB,
                                       uint& m, uint cur, int rowbase, int cx,
                                       long long* accA, long long* accB) {
    const int* pA[N];
    const int* pB[N];
    int sm[N];
#pragma unroll
    for (int u = 0; u < N; ++u) {
        int bb = __ffs((int)m);
        int k  = (bb ? bb : 1) - 1;
        int row = rfl(bb ? (rowbase + k) : ZR);
        int pos = rfl(bb ? (int)((cur >> k) & 1u) : 1);
        sm[u] = pos ? 0 : -1;
        size_t off = ((size_t)row << 8) + (size_t)cx;
        pA[u] = tabA + off;
        pB[u] = tabB + off;
        m &= (m - 1u);
    }
    int4 va[N], vb[N];
#pragma unroll
    for (int u = 0; u < N; ++u) { va[u] = *(const int4*)pA[u]; vb[u] = *(const int4*)pB[u]; }
#pragma unroll
    for (int u = 0; u < N; ++u) {
        accA[0] += (long long)((va[u].x ^ sm[u]) - sm[u]);
        accA[1] += (long long)((va[u].y ^ sm[u]) - sm[u]);
        accA[2] += (long long)((va[u].z ^ sm[u]) - sm[u]);
        accA[3] += (long long)((va[u].w ^ sm[u]) - sm[u]);
        accB[0] += (long long)((vb[u].x ^ sm[u]) - sm[u]);
        accB[1] += (long long)((vb[u].y ^ sm[u]) - sm[u]);
        accB[2] += (long long)((vb[u].z ^ sm[u]) - sm[u]);
        accB[3] += (long long)((vb[u].w ^ sm[u]) - sm[u]);
    }
}

// Dual-table gather over a 64-bit toggle mask (both 32-bit words), committed via
// LDS int64 atomics into the [c][lane] delta layout (stride DSTR -> 2-way banks).
__device__ __forceinline__ void gatherPair(const int* __restrict__ tabA, const int* __restrict__ tabB,
                                           ull tog, ull cur, int rowbase, int lane,
                                           long long* dstA, long long* dstB) {
    long long accA[4] = {0, 0, 0, 0}, accB[4] = {0, 0, 0, 0};
    int cx = lane << 2;
    uint m  = (uint)tog;         uint c0 = (uint)cur;
    uint mh = (uint)(tog >> 32); uint c1 = (uint)(cur >> 32);
    while (m) {
        int pc = rfl(__popc(m));
        if (pc > 4)      gstep2<8>(tabA, tabB, m, c0, rowbase, cx, accA, accB);
        else if (pc > 2) gstep2<4>(tabA, tabB, m, c0, rowbase, cx, accA, accB);
        else             gstep2<2>(tabA, tabB, m, c0, rowbase, cx, accA, accB);
    }
    while (mh) {
        int pc = rfl(__popc(mh));
        if (pc > 4)      gstep2<8>(tabA, tabB, mh, c1, rowbase + 32, cx, accA, accB);
        else if (pc > 2) gstep2<4>(tabA, tabB, mh, c1, rowbase + 32, cx, accA, accB);
        else             gstep2<2>(tabA, tabB, mh, c1, rowbase + 32, cx, accA, accB);
    }
#pragma unroll
    for (int c = 0; c < 4; ++c) {
        atomicAdd((ull*)&dstA[c * DSTR + lane], (ull)accA[c]);
        atomicAdd((ull*)&dstB[c * DSTR + lane], (ull)accB[c]);
    }
}

#define INV30 9.31322574615478515625e-10   // 2^-30, exact

// 9-wave (576-thread) SINGLE-barrier pipeline.
// Rotating zeroed delta buffers (2 slots): gather(i) atomic-adds into slot i&1;
// consumers fold slot (i-1)&1 into REGISTER totals and zero it. Read-slot !=
// write-slot every interval => one barrier per step suffices.
// Waves 0-3: L1 neuron update(i) [reg total TV1] + ballot (regs) + own-word dual
//   gather (W2Tq,V1q) + wx(i+1) from register W1 row (fills gather's load shadow).
// Waves 4-7: L2 update(i-1) [reg totals TW2,TV2] + ballot + dual gather (WTq,V2q).
// Wave 8: x(i+2) prefetch + output layer F(i-2) [reg totals TOq].
__global__ __launch_bounds__(576, 1) void snn_main(
    const float* __restrict__ x,
    const float* __restrict__ W1, const float* __restrict__ b1,
    const float* __restrict__ beta1,
    const float* __restrict__ b2, const float* __restrict__ beta2,
    const int* __restrict__ V1q, const int* __restrict__ V2q,
    const int* __restrict__ W2Tq, const int* __restrict__ WTq,
    const float* __restrict__ alpha_out, const float* __restrict__ beta_out,
    float* __restrict__ out)
{
    __shared__ float xts[2][FF];                       // x[t] double buffer
    // delta buffers: drive d (0=V1 1=W2 2=V2 3=O) x slot p x [c][lane] (stride DSTR)
    __shared__ __align__(16) long long dAll[4 * 2 * 4 * DSTR];   // ~17 KB

#define DSL(d, p) (dAll + (((d) * 2 + (p)) * 4) * DSTR)

    const int tid  = threadIdx.x;
    const int wid  = tid >> 6;
    const int lane = tid & 63;
    const int b    = blockIdx.x;
    const float* xg = x + (size_t)b * TT * FF;

    // ---- init ----
    for (int idx = tid; idx < 4 * 2 * 4 * DSTR; idx += 576) dAll[idx] = 0;
    if (tid < FF) { xts[0][tid] = xg[tid]; xts[1][tid] = xg[FF + tid]; }

    // L1 state (tid 0..255): W1 row in registers, drive total in register
    float syn1 = 0.f, mem1 = 0.f, beta1r = 0.f, b1r = 0.f, wxv = 0.f;
    float w1r[FF];
    long long TV1 = 0;
    bool spk1 = false;
    ull cur1 = 0ull;
    if (tid < HH) {
        beta1r = beta1[tid]; b1r = b1[tid];
#pragma unroll
        for (int f = 0; f < FF; ++f) w1r[f] = W1[tid * FF + f];
    }

    // L2 state (tid 256..511)
    float syn2 = 0.f, mem2 = 0.f, beta2r = 0.f, b2r = 0.f;
    long long TW2 = 0, TV2 = 0;
    bool spk2 = false;
    ull cur2 = 0ull;
    if (wid >= 4 && wid < 8) { beta2r = beta2[tid - HH]; b2r = b2[tid - HH]; }

    // output state (wave 8)
    float synO[4] = {0,0,0,0}, memO[4] = {0,0,0,0}, accO[4] = {0,0,0,0};
    float aOr[4] = {0,0,0,0}, bOr[4] = {0,0,0,0};
    long long TOq[4] = {0, 0, 0, 0};
    bool  spkO[4] = {false,false,false,false};
    if (wid == 8) {
#pragma unroll
        for (int r = 0; r < 4; ++r) {
            int o = lane + (r << 6);
            if (o < OO) { aOr[r] = alpha_out[o]; bOr[r] = beta_out[o]; }
        }
    }
    __syncthreads();
    if (tid < HH) {   // wx for t=0
        float wx = b1r;
#pragma unroll
        for (int f = 0; f < FF; ++f) wx = fmaf(xts[0][f], w1r[f], wx);
        wxv = wx;
    }
    __syncthreads();  // protect xts[0] before wave-8's interval-0 rewrite

    for (int i = 0; i < TT + 2; ++i) {
        const int rp = (i - 1) & 1;   // fold slot (written last interval)
        const int wp = i & 1;         // gather-commit slot
        if (wid < 4) {
            // ---- L1: update(i) + gather + wx(i+1) ----
            if (i < TT) {
                long long* slot = DSL(0, rp);
                int idx = (tid & 3) * DSTR + (tid >> 2);
                TV1 += slot[idx]; slot[idx] = 0;
                float g1 = (float)((double)TV1 * INV30);
                syn1 = fmaf(0.95f, syn1, wxv + g1);
                mem1 = fmaf(beta1r, mem1, syn1) - (spk1 ? 1.f : 0.f);
                spk1 = mem1 > 1.0f;
                ull bal = __ballot(spk1 ? 1 : 0);
                ull tog = cur1 ^ bal;
                cur1 = bal;
                if (tog) gatherPair(W2Tq, V1q, tog, cur1, wid << 6, lane,
                                    DSL(1, wp), DSL(0, wp));
                if ((i + 1) < TT) {
                    const float* xx = xts[(i + 1) & 1];
                    float wx = b1r;
#pragma unroll
                    for (int f = 0; f < FF; ++f) wx = fmaf(xx[f], w1r[f], wx);
                    wxv = wx;
                }
            }
        } else if (wid < 8) {
            // ---- L2: update(i-1) + gather ----
            if (i >= 1 && i <= TT) {
                int j = tid - HH;
                int idx = (j & 3) * DSTR + (j >> 2);
                long long* sA = DSL(1, rp);
                long long* sB = DSL(2, rp);
                TW2 += sA[idx]; sA[idx] = 0;
                TV2 += sB[idx]; sB[idx] = 0;
                float gA = (float)((double)TW2 * INV30);
                float gB = (float)((double)TV2 * INV30);
                syn2 = fmaf(0.95f, syn2, b2r + gA + gB);
                mem2 = fmaf(beta2r, mem2, syn2) - (spk2 ? 1.f : 0.f);
                spk2 = mem2 > 1.0f;
                ull bal = __ballot(spk2 ? 1 : 0);
                ull tog = cur2 ^ bal;
                cur2 = bal;
                if (tog) gatherPair(WTq, V2q, tog, cur2, (wid - 4) << 6, lane,
                                    DSL(3, wp), DSL(2, wp));
            }
        } else {
            // ---- wave 8: x prefetch (issue early, commit late) + F(i-2) ----
            float xpf = 0.f;
            const bool pf = (lane < FF) && ((i + 2) < TT);
            if (pf) xpf = xg[(size_t)(i + 2) * FF + lane];
            if (i >= 2) {
                int tF = i - 2;
                long long* sO = DSL(3, rp);
                float mmax = -3.402823466e38f;
#pragma unroll
                for (int r = 0; r < 4; ++r) {
                    int o = lane + (r << 6);
                    if (o < OO) {
                        int idx = (o & 3) * DSTR + (o >> 2);
                        TOq[r] += sO[idx]; sO[idx] = 0;
                        float ot = (float)((double)TOq[r] * INV30);
                        synO[r] = fmaf(aOr[r], synO[r], ot);
                        memO[r] = fmaf(bOr[r], memO[r], synO[r]) - (spkO[r] ? 1.f : 0.f);
                        spkO[r] = memO[r] > 1.0f;
                        mmax = fmaxf(mmax, memO[r]);
                    } else {
                        int idx = (o & 3) * DSTR + (o >> 2);
                        if (o < HH) sO[idx] = 0;   // keep slot clean (always zero anyway)
                    }
                }
#pragma unroll
                for (int off = 32; off; off >>= 1) mmax = fmaxf(mmax, __shfl_xor(mmax, off, 64));
                float ex[4]; float se = 0.f;
#pragma unroll
                for (int r = 0; r < 4; ++r) {
                    int o = lane + (r << 6);
                    ex[r] = (o < OO) ? expf(memO[r] - mmax) : 0.f;
                    se += ex[r];
                }
#pragma unroll
                for (int off = 32; off; off >>= 1) se += __shfl_xor(se, off, 64);
                if (tF > 10) {
#pragma unroll
                    for (int r = 0; r < 4; ++r) accO[r] += ex[r] / se;
                }
            }
            if (pf) xts[i & 1][lane] = xpf;
        }
        __syncthreads();
    }

    if (wid == 8) {
#pragma unroll
        for (int r = 0; r < 4; ++r) {
            int o = lane + (r << 6);
            if (o < OO) out[(size_t)b * OO + o] = accO[r];
        }
    }
}

// one-shot prep: padded 257x256 int32 fixed-point (2^30) tables, zero diagonal
// (V1q/V2q), zero row 256, WTq cols >= 200 zero.
__global__ void prep_kernel(const float* __restrict__ Vrec1, const float* __restrict__ Vrec2,
                            const float* __restrict__ W2, const float* __restrict__ Wout,
                            int* __restrict__ V1q, int* __restrict__ V2q,
                            int* __restrict__ W2Tq, int* __restrict__ WTq) {
    int idx = blockIdx.x * blockDim.x + threadIdx.x;   // 257*256 entries
    if (idx >= 257 * 256) return;
    int r = idx >> 8, c = idx & 255;
    float v1 = 0.f, v2 = 0.f, w2 = 0.f, wo = 0.f;
    if (r < 256) {
        if (r != c) { v1 = Vrec1[r * HH + c]; v2 = Vrec2[r * HH + c]; }
        w2 = W2[c * HH + r];
        if (c < OO) wo = Wout[c * HH + r];
    }
    const float S = 1073741824.0f;   // 2^30
    V1q[idx]  = __float2int_rn(v1 * S);
    V2q[idx]  = __float2int_rn(v2 * S);
    W2Tq[idx] = __float2int_rn(w2 * S);
    WTq[idx]  = __float2int_rn(wo * S);
}

extern "C" void kernel_launch(void* const* d_in, const int* in_sizes, int n_in,
                              void* d_out, int out_size, void* d_ws, size_t ws_size,
                              hipStream_t stream) {
    const float* x       = (const float*)d_in[0];
    const float* W1      = (const float*)d_in[1];
    const float* b1      = (const float*)d_in[2];
    const float* Vrec1   = (const float*)d_in[3];
    const float* beta1   = (const float*)d_in[4];
    const float* W2      = (const float*)d_in[5];
    const float* b2      = (const float*)d_in[6];
    const float* Vrec2   = (const float*)d_in[7];
    const float* beta2   = (const float*)d_in[8];
    const float* Wout    = (const float*)d_in[9];
    const float* alpha_o = (const float*)d_in[10];
    const float* beta_o  = (const float*)d_in[11];

    const int TBL = 257 * 256;       // int32 per padded table
    int* V1q  = (int*)d_ws;
    int* V2q  = V1q + TBL;
    int* W2Tq = V2q + TBL;
    int* WTq  = W2Tq + TBL;          // total ~1.05 MB of ws

    prep_kernel<<<(TBL + 255) / 256, 256, 0, stream>>>(Vrec1, Vrec2, W2, Wout,
                                                       V1q, V2q, W2Tq, WTq);
    snn_main<<<128, 576, 0, stream>>>(x, W1, b1, beta1, b2, beta2,
                                      V1q, V2q, W2Tq, WTq,
                                      alpha_o, beta_o, (float*)d_out);
}